// Round 1
// baseline (89653.534 us; speedup 1.0000x reference)
//
#include <hip/hip_runtime.h>
#include <hip/hip_bf16.h>
#include <math.h>

// Problem dims (fixed by the reference)
#define T_DIM   512
#define B_DIM   64
#define INP_DIM 512
#define HS_DIM  2048
#define OUT_DIM 512

// Persistent device-global scratch (avoids any dependence on ws_size).
// All buffers are fully rewritten every call -> deterministic across graph replays.
static __device__ float g_dataT[(size_t)T_DIM * INP_DIM * B_DIM]; // [t][k][b]
static __device__ float g_prex[(size_t)T_DIM * HS_DIM * B_DIM];   // [t][j][b] = x@Wih.T + bih + bhh
static __device__ float g_hT[HS_DIM * B_DIM];                     // [j][b]
static __device__ float g_rT[HS_DIM * B_DIM];                     // [j][b]
static __device__ float g_potT[HS_DIM * B_DIM];                   // [j][b]

__global__ __launch_bounds__(256) void zero_state_kernel() {
    int i = blockIdx.x * 256 + threadIdx.x;
    if (i < HS_DIM * B_DIM) { g_hT[i] = 0.f; g_potT[i] = 0.f; }
}

// data [t][b][k] -> g_dataT [t][k][b], via LDS tiles (conflict-free with +1 pad)
__global__ __launch_bounds__(256) void transpose_data_kernel(const float* __restrict__ data) {
    __shared__ float tile[64][65];
    const int t = blockIdx.x;
    const float* src = data + (size_t)t * B_DIM * INP_DIM;
    float* dst = g_dataT + (size_t)t * INP_DIM * B_DIM;
    for (int kt = 0; kt < INP_DIM / 64; ++kt) {
        const int k0 = kt * 64;
        __syncthreads();
        for (int i = threadIdx.x; i < 64 * 64; i += 256) {
            int b = i >> 6, kk = i & 63;
            tile[b][kk] = src[b * INP_DIM + k0 + kk];
        }
        __syncthreads();
        for (int i = threadIdx.x; i < 64 * 64; i += 256) {
            int k = i >> 6, b2 = i & 63;
            dst[(size_t)(k0 + k) * B_DIM + b2] = tile[b2][k];
        }
    }
}

// g_prex[t][j][b] = bih[j] + bhh[j] + sum_k dataT[t][k][b] * Wih[j][k]
// grid (HS/32, T), 256 thr = 4 waves; wave owns 8 cols; lane = batch row
__global__ __launch_bounds__(256) void prex_kernel(const float* __restrict__ Wih,
                                                   const float* __restrict__ bih,
                                                   const float* __restrict__ bhh) {
    __shared__ float lds[128 * B_DIM]; // 32 KiB K-chunk of dataT[t]
    const int t = blockIdx.y;
    const int lane = threadIdx.x & 63;
    const int wv = __builtin_amdgcn_readfirstlane(threadIdx.x >> 6);
    const int j0 = blockIdx.x * 32 + wv * 8;
    const float* xT = g_dataT + (size_t)t * INP_DIM * B_DIM;
    float acc[8] = {};
    for (int k0 = 0; k0 < INP_DIM; k0 += 128) {
        __syncthreads();
        {
            const float4* s4 = (const float4*)(xT + (size_t)k0 * B_DIM);
            float4* d4 = (float4*)lds;
            for (int i = threadIdx.x; i < 128 * B_DIM / 4; i += 256) d4[i] = s4[i];
        }
        __syncthreads();
        for (int k = 0; k < 128; k += 4) {
            float w[8][4];
            #pragma unroll
            for (int c = 0; c < 8; ++c)
                #pragma unroll
                for (int u = 0; u < 4; ++u)
                    w[c][u] = Wih[(size_t)(j0 + c) * INP_DIM + k0 + k + u];
            #pragma unroll
            for (int u = 0; u < 4; ++u) {
                float hv = lds[(k + u) * B_DIM + lane];
                #pragma unroll
                for (int c = 0; c < 8; ++c) acc[c] += hv * w[c][u];
            }
        }
    }
    #pragma unroll
    for (int c = 0; c < 8; ++c) {
        int j = j0 + c;
        g_prex[((size_t)t * HS_DIM + j) * B_DIM + lane] = acc[c] + bih[j] + bhh[j];
    }
}

// r = tanh(prex[t] + h @ Whh.T)  -> g_rT
// grid HS/8 = 256 blocks, 256 thr = 4 waves; wave owns 2 cols; lane = batch row
__global__ __launch_bounds__(256) void step_rnn_kernel(const float* __restrict__ Whh, int t) {
    __shared__ float lds[256 * B_DIM]; // 64 KiB K-chunk of hT
    const int lane = threadIdx.x & 63;
    const int wv = __builtin_amdgcn_readfirstlane(threadIdx.x >> 6);
    const int j0 = blockIdx.x * 8 + wv * 2;
    float acc0 = 0.f, acc1 = 0.f;
    for (int k0 = 0; k0 < HS_DIM; k0 += 256) {
        __syncthreads();
        {
            const float4* s4 = (const float4*)(g_hT + (size_t)k0 * B_DIM);
            float4* d4 = (float4*)lds;
            for (int i = threadIdx.x; i < 256 * B_DIM / 4; i += 256) d4[i] = s4[i];
        }
        __syncthreads();
        for (int k = 0; k < 256; k += 8) {
            float w0[8], w1[8];
            #pragma unroll
            for (int u = 0; u < 8; ++u) {
                w0[u] = Whh[(size_t)j0 * HS_DIM + k0 + k + u];
                w1[u] = Whh[(size_t)(j0 + 1) * HS_DIM + k0 + k + u];
            }
            #pragma unroll
            for (int u = 0; u < 8; ++u) {
                float hv = lds[(k + u) * B_DIM + lane];
                acc0 += hv * w0[u];
                acc1 += hv * w1[u];
            }
        }
    }
    const size_t base = (size_t)t * HS_DIM * B_DIM;
    g_rT[(size_t)j0 * B_DIM + lane] =
        tanhf(g_prex[base + (size_t)j0 * B_DIM + lane] + acc0);
    g_rT[(size_t)(j0 + 1) * B_DIM + lane] =
        tanhf(g_prex[base + (size_t)(j0 + 1) * B_DIM + lane] + acc1);
}

// p = pot + r @ Wp.T + bp ; act = relu(p) ; pot = min(p,0)*decay ; h = act
__global__ __launch_bounds__(256) void step_pglu_kernel(const float* __restrict__ Wp,
                                                        const float* __restrict__ bp,
                                                        const float* __restrict__ decay) {
    __shared__ float lds[256 * B_DIM]; // 64 KiB K-chunk of rT
    const int lane = threadIdx.x & 63;
    const int wv = __builtin_amdgcn_readfirstlane(threadIdx.x >> 6);
    const int j0 = blockIdx.x * 8 + wv * 2;
    float acc0 = 0.f, acc1 = 0.f;
    for (int k0 = 0; k0 < HS_DIM; k0 += 256) {
        __syncthreads();
        {
            const float4* s4 = (const float4*)(g_rT + (size_t)k0 * B_DIM);
            float4* d4 = (float4*)lds;
            for (int i = threadIdx.x; i < 256 * B_DIM / 4; i += 256) d4[i] = s4[i];
        }
        __syncthreads();
        for (int k = 0; k < 256; k += 8) {
            float w0[8], w1[8];
            #pragma unroll
            for (int u = 0; u < 8; ++u) {
                w0[u] = Wp[(size_t)j0 * HS_DIM + k0 + k + u];
                w1[u] = Wp[(size_t)(j0 + 1) * HS_DIM + k0 + k + u];
            }
            #pragma unroll
            for (int u = 0; u < 8; ++u) {
                float hv = lds[(k + u) * B_DIM + lane];
                acc0 += hv * w0[u];
                acc1 += hv * w1[u];
            }
        }
    }
    {
        float p0 = g_potT[(size_t)j0 * B_DIM + lane] + acc0 + bp[j0];
        g_hT[(size_t)j0 * B_DIM + lane] = fmaxf(p0, 0.f);
        g_potT[(size_t)j0 * B_DIM + lane] = fminf(p0, 0.f) * decay[j0];
    }
    {
        float p1 = g_potT[(size_t)(j0 + 1) * B_DIM + lane] + acc1 + bp[j0 + 1];
        g_hT[(size_t)(j0 + 1) * B_DIM + lane] = fmaxf(p1, 0.f);
        g_potT[(size_t)(j0 + 1) * B_DIM + lane] = fminf(p1, 0.f) * decay[j0 + 1];
    }
}

// out[b][o] = bout[o] + sum_j hT[j][b] * Wout[o][j]
// grid OUT/16 = 32 blocks; wave owns 4 cols
__global__ __launch_bounds__(256) void out_kernel(const float* __restrict__ Wout,
                                                  const float* __restrict__ bout,
                                                  float* __restrict__ out) {
    __shared__ float lds[256 * B_DIM]; // 64 KiB K-chunk of hT
    const int lane = threadIdx.x & 63;
    const int wv = __builtin_amdgcn_readfirstlane(threadIdx.x >> 6);
    const int o0 = blockIdx.x * 16 + wv * 4;
    float acc[4] = {};
    for (int k0 = 0; k0 < HS_DIM; k0 += 256) {
        __syncthreads();
        {
            const float4* s4 = (const float4*)(g_hT + (size_t)k0 * B_DIM);
            float4* d4 = (float4*)lds;
            for (int i = threadIdx.x; i < 256 * B_DIM / 4; i += 256) d4[i] = s4[i];
        }
        __syncthreads();
        for (int k = 0; k < 256; k += 4) {
            float w[4][4];
            #pragma unroll
            for (int c = 0; c < 4; ++c)
                #pragma unroll
                for (int u = 0; u < 4; ++u)
                    w[c][u] = Wout[(size_t)(o0 + c) * HS_DIM + k0 + k + u];
            #pragma unroll
            for (int u = 0; u < 4; ++u) {
                float hv = lds[(k + u) * B_DIM + lane];
                #pragma unroll
                for (int c = 0; c < 4; ++c) acc[c] += hv * w[c][u];
            }
        }
    }
    #pragma unroll
    for (int c = 0; c < 4; ++c)
        out[(size_t)lane * OUT_DIM + o0 + c] = acc[c] + bout[o0 + c];
}

extern "C" void kernel_launch(void* const* d_in, const int* in_sizes, int n_in,
                              void* d_out, int out_size, void* d_ws, size_t ws_size,
                              hipStream_t stream) {
    const float* data  = (const float*)d_in[0];
    const float* Wih   = (const float*)d_in[1];
    const float* bih   = (const float*)d_in[2];
    const float* Whh   = (const float*)d_in[3];
    const float* bhh   = (const float*)d_in[4];
    const float* Wp    = (const float*)d_in[5];
    const float* bp    = (const float*)d_in[6];
    const float* decay = (const float*)d_in[7];
    const float* Wout  = (const float*)d_in[8];
    const float* bout  = (const float*)d_in[9];
    float* out = (float*)d_out;

    zero_state_kernel<<<(HS_DIM * B_DIM + 255) / 256, 256, 0, stream>>>();
    transpose_data_kernel<<<T_DIM, 256, 0, stream>>>(data);
    prex_kernel<<<dim3(HS_DIM / 32, T_DIM), 256, 0, stream>>>(Wih, bih, bhh);
    for (int t = 0; t < T_DIM; ++t) {
        step_rnn_kernel<<<HS_DIM / 8, 256, 0, stream>>>(Whh, t);
        step_pglu_kernel<<<HS_DIM / 8, 256, 0, stream>>>(Wp, bp, decay);
    }
    out_kernel<<<OUT_DIM / 16, 256, 0, stream>>>(Wout, bout, out);
}

// Round 3
// 55230.023 us; speedup vs baseline: 1.6233x; 1.6233x over previous
//
#include <hip/hip_runtime.h>
#include <math.h>

// Problem dims (fixed by the reference)
#define T_DIM   512
#define B_DIM   64
#define INP_DIM 512
#define HS_DIM  2048
#define OUT_DIM 512

// Persistent device-global scratch. All buffers fully rewritten every call.
static __device__ float g_dataT[(size_t)T_DIM * INP_DIM * B_DIM]; // [t][k][b]
static __device__ float g_prex[(size_t)T_DIM * HS_DIM * B_DIM];   // [t][j][b] = x@Wih.T + bih + bhh
static __device__ float g_hT4[HS_DIM * B_DIM];                    // quad-packed [j/4][b][4]
static __device__ float g_rT4[HS_DIM * B_DIM];                    // quad-packed [j/4][b][4]
static __device__ float g_potT[HS_DIM * B_DIM];                   // linear [j][b]

// async global->LDS, 16B per lane (wave writes lds_base + lane*16)
__device__ __forceinline__ void async_ld16(const float* g, float* l) {
    __builtin_amdgcn_global_load_lds(
        (const __attribute__((address_space(1))) void*)g,
        (__attribute__((address_space(3))) void*)l, 16, 0, 0);
}

__global__ __launch_bounds__(256) void zero_state_kernel() {
    int i = blockIdx.x * 256 + threadIdx.x;
    if (i < HS_DIM * B_DIM) { g_hT4[i] = 0.f; g_potT[i] = 0.f; }
}

// data [t][b][k] -> g_dataT [t][k][b]
__global__ __launch_bounds__(256) void transpose_data_kernel(const float* __restrict__ data) {
    __shared__ float tile[64][65];
    const int t = blockIdx.x;
    const float* src = data + (size_t)t * B_DIM * INP_DIM;
    float* dst = g_dataT + (size_t)t * INP_DIM * B_DIM;
    for (int kt = 0; kt < INP_DIM / 64; ++kt) {
        const int k0 = kt * 64;
        __syncthreads();
        for (int i = threadIdx.x; i < 64 * 64; i += 256) {
            int b = i >> 6, kk = i & 63;
            tile[b][kk] = src[b * INP_DIM + k0 + kk];
        }
        __syncthreads();
        for (int i = threadIdx.x; i < 64 * 64; i += 256) {
            int k = i >> 6, b2 = i & 63;
            dst[(size_t)(k0 + k) * B_DIM + b2] = tile[b2][k];
        }
    }
}

// g_prex[t][j][b] = bih[j] + bhh[j] + sum_k dataT[t][k][b] * Wih[j][k]
__global__ __launch_bounds__(256) void prex_kernel(const float* __restrict__ Wih,
                                                   const float* __restrict__ bih,
                                                   const float* __restrict__ bhh) {
    __shared__ float lds[128 * B_DIM];
    const int t = blockIdx.y;
    const int lane = threadIdx.x & 63;
    const int wv = __builtin_amdgcn_readfirstlane(threadIdx.x >> 6);
    const int j0 = blockIdx.x * 32 + wv * 8;
    const float* xT = g_dataT + (size_t)t * INP_DIM * B_DIM;
    float acc[8] = {};
    for (int k0 = 0; k0 < INP_DIM; k0 += 128) {
        __syncthreads();
        {
            const float4* s4 = (const float4*)(xT + (size_t)k0 * B_DIM);
            float4* d4 = (float4*)lds;
            for (int i = threadIdx.x; i < 128 * B_DIM / 4; i += 256) d4[i] = s4[i];
        }
        __syncthreads();
        for (int k = 0; k < 128; k += 4) {
            float w[8][4];
            #pragma unroll
            for (int c = 0; c < 8; ++c)
                #pragma unroll
                for (int u = 0; u < 4; ++u)
                    w[c][u] = Wih[(size_t)(j0 + c) * INP_DIM + k0 + k + u];
            #pragma unroll
            for (int u = 0; u < 4; ++u) {
                float hv = lds[(k + u) * B_DIM + lane];
                #pragma unroll
                for (int c = 0; c < 8; ++c) acc[c] += hv * w[c][u];
            }
        }
    }
    #pragma unroll
    for (int c = 0; c < 8; ++c) {
        int j = j0 + c;
        g_prex[((size_t)t * HS_DIM + j) * B_DIM + lane] = acc[c] + bih[j] + bhh[j];
    }
}

// One recurrent GEMM step. PHASE 0: r = tanh(prex[t] + h@Whh.T) -> g_rT4
//                          PHASE 1: p = pot + r@Wp.T + bp; h=relu(p); pot=min(p,0)*decay
// 256 blocks x 4 waves. Block owns 8 output cols. Wave wv owns K-quarter
// [wv*512, wv*512+512), staged wave-privately (global_load_lds, double-buffered,
// no barriers in main loop), in-block split-K reduction at the end.
template <int PHASE>
__global__ __launch_bounds__(256) void step_kernel(const float* __restrict__ W,
                                                   const float* __restrict__ bp,
                                                   const float* __restrict__ decay,
                                                   int t) {
    // staging: 4 waves * 2 bufs * 8KB = 64KB; reduction: 8KB
    __shared__ float lds[16384 + 2048];
    const int lane = threadIdx.x & 63;
    const int wv = __builtin_amdgcn_readfirstlane(threadIdx.x >> 6);
    const int j0 = blockIdx.x * 8;
    const float* src = (PHASE == 0) ? g_hT4 : g_rT4; // quad-packed [k4][b][4]
    const int kbase4 = wv * 128; // wave's k4 range: [kbase4, kbase4+128)
    float* myl = &lds[wv * 4096];

    float acc[8] = {};

    // prologue: issue chunk 0 (8 k4-rows = 32 k values = 8KB) into buf 0
    #pragma unroll
    for (int r = 0; r < 8; ++r)
        async_ld16(src + (size_t)(kbase4 + r) * 256 + lane * 4, myl + r * 256);

    for (int ch = 0; ch < 16; ++ch) {
        // wait for chunk ch (and any strays) to land in LDS
        asm volatile("s_waitcnt vmcnt(0)" ::: "memory");
        // issue chunk ch+1 into the other buffer (overlaps with compute below)
        if (ch < 15) {
            float* nl = myl + (((ch + 1) & 1) << 11);
            #pragma unroll
            for (int r = 0; r < 8; ++r)
                async_ld16(src + (size_t)(kbase4 + (ch + 1) * 8 + r) * 256 + lane * 4,
                           nl + r * 256);
        }
        const float* cl = myl + ((ch & 1) << 11);
        // weights at wave-uniform addresses -> scalar loads
        const float* Wk = W + (size_t)j0 * HS_DIM + (size_t)(kbase4 + ch * 8) * 4;
        #pragma unroll
        for (int r = 0; r < 8; ++r) {
            float4 h4 = *(const float4*)(cl + r * 256 + lane * 4); // ds_read_b128, conflict-free
            #pragma unroll
            for (int c = 0; c < 8; ++c) {
                const float* w = Wk + (size_t)c * HS_DIM + r * 4;
                acc[c] = fmaf(h4.x, w[0], acc[c]);
                acc[c] = fmaf(h4.y, w[1], acc[c]);
                acc[c] = fmaf(h4.z, w[2], acc[c]);
                acc[c] = fmaf(h4.w, w[3], acc[c]);
            }
        }
    }

    // in-block split-K reduction: red[wv][c][lane]
    float* red = &lds[16384];
    #pragma unroll
    for (int c = 0; c < 8; ++c) red[(wv * 8 + c) * 64 + lane] = acc[c];
    __syncthreads();

    #pragma unroll
    for (int s = 0; s < 2; ++s) {
        int idx = threadIdx.x + s * 256; // 512 slots = 8 cols x 64 b
        int c = idx >> 6, b = idx & 63;
        int j = j0 + c;
        float sum = red[(0 * 8 + c) * 64 + b] + red[(1 * 8 + c) * 64 + b] +
                    red[(2 * 8 + c) * 64 + b] + red[(3 * 8 + c) * 64 + b];
        if (PHASE == 0) {
            float rr = tanhf(g_prex[((size_t)t * HS_DIM + j) * B_DIM + b] + sum);
            g_rT4[(size_t)(j >> 2) * 256 + b * 4 + (j & 3)] = rr;
        } else {
            float p = g_potT[(size_t)j * B_DIM + b] + sum + bp[j];
            g_hT4[(size_t)(j >> 2) * 256 + b * 4 + (j & 3)] = fmaxf(p, 0.f);
            g_potT[(size_t)j * B_DIM + b] = fminf(p, 0.f) * decay[j];
        }
    }
}

// out[b][o] = bout[o] + sum_j h[j][b] * Wout[o][j], h quad-packed -> float4 loads
__global__ __launch_bounds__(256) void out_kernel(const float* __restrict__ Wout,
                                                  const float* __restrict__ bout,
                                                  float* __restrict__ out) {
    const int lane = threadIdx.x & 63;
    const int wv = __builtin_amdgcn_readfirstlane(threadIdx.x >> 6);
    const int o0 = blockIdx.x * 16 + wv * 4;
    float acc[4] = {};
    for (int k4 = 0; k4 < HS_DIM / 4; ++k4) {
        float4 h4 = *(const float4*)&g_hT4[(size_t)k4 * 256 + lane * 4];
        #pragma unroll
        for (int c = 0; c < 4; ++c) {
            const float* w = Wout + (size_t)(o0 + c) * HS_DIM + (size_t)k4 * 4;
            acc[c] = fmaf(h4.x, w[0], acc[c]);
            acc[c] = fmaf(h4.y, w[1], acc[c]);
            acc[c] = fmaf(h4.z, w[2], acc[c]);
            acc[c] = fmaf(h4.w, w[3], acc[c]);
        }
    }
    #pragma unroll
    for (int c = 0; c < 4; ++c)
        out[(size_t)lane * OUT_DIM + o0 + c] = acc[c] + bout[o0 + c];
}

extern "C" void kernel_launch(void* const* d_in, const int* in_sizes, int n_in,
                              void* d_out, int out_size, void* d_ws, size_t ws_size,
                              hipStream_t stream) {
    const float* data  = (const float*)d_in[0];
    const float* Wih   = (const float*)d_in[1];
    const float* bih   = (const float*)d_in[2];
    const float* Whh   = (const float*)d_in[3];
    const float* bhh   = (const float*)d_in[4];
    const float* Wp    = (const float*)d_in[5];
    const float* bp    = (const float*)d_in[6];
    const float* decay = (const float*)d_in[7];
    const float* Wout  = (const float*)d_in[8];
    const float* bout  = (const float*)d_in[9];
    float* out = (float*)d_out;

    zero_state_kernel<<<(HS_DIM * B_DIM + 255) / 256, 256, 0, stream>>>();
    transpose_data_kernel<<<T_DIM, 256, 0, stream>>>(data);
    prex_kernel<<<dim3(HS_DIM / 32, T_DIM), 256, 0, stream>>>(Wih, bih, bhh);
    for (int t = 0; t < T_DIM; ++t) {
        step_kernel<0><<<HS_DIM / 8, 256, 0, stream>>>(Whh, bp, decay, t);
        step_kernel<1><<<HS_DIM / 8, 256, 0, stream>>>(Wp, bp, decay, t);
    }
    out_kernel<<<OUT_DIM / 16, 256, 0, stream>>>(Wout, bout, out);
}